// Round 10
// baseline (1978.553 us; speedup 1.0000x reference)
//
#include <hip/hip_runtime.h>
#include <hip/hip_bf16.h>
#include <math.h>

// AudioModelV3: 7-block xLSTM (blocks 1,4 = sLSTM+FFN; others mLSTM).
// R10: slstm_rec v5 — 4 waves (256 thr), one (g,o)/thread, weights in LDS
// (stride-68, conflict-free). Theory: R6-R9 all ~200us regardless of weight
// residency => per-step cost is barrier/latency with 8 waves, not BW. Halve
// the waves, drop the shfl/split-K, halve redundant gate math.

#define B_    64
#define S_    199
#define E_    256
#define NTOK  (B_*S_)          // 12736
#define NQT   13               // ceil(199/16)

typedef __attribute__((ext_vector_type(8))) short short8;
typedef __attribute__((ext_vector_type(4))) float floatx4;
typedef unsigned short ushort_t;

__device__ __forceinline__ float sigmoidf_(float x) { return 1.f / (1.f + expf(-x)); }
__device__ __forceinline__ float siluf_(float x) { return x / (1.f + expf(-x)); }
__device__ __forceinline__ float logsigf_(float x) { return fminf(x, 0.f) - log1pf(expf(-fabsf(x))); }

__device__ __forceinline__ ushort_t f2b(float f) {   // fp32 -> bf16 (RNE)
    union { float f; unsigned u; } v; v.f = f;
    unsigned r = (v.u + 0x7fffu + ((v.u >> 16) & 1u)) >> 16;
    return (ushort_t)r;
}
__device__ __forceinline__ float bf2f(ushort_t u) {
    union { unsigned u; float f; } v; v.u = ((unsigned)u) << 16;
    return v.f;
}

// ---------------- fp32 -> bf16 pack of all GEMM weights (one launch) ---------
__global__ void cvt_all(const float* __restrict__ pu, const float* __restrict__ pd,
                        const float* __restrict__ fu, const float* __restrict__ fd,
                        ushort_t* __restrict__ out, int n4) {
    int i = blockIdx.x * 256 + threadIdx.x;
    if (i >= n4) return;
    int e = i * 4;
    const float* src;
    if (e < 1310720)      src = pu + e;
    else if (e < 1966080) src = pd + (e - 1310720);
    else if (e < 2359296) src = fu + (e - 1966080);
    else                  src = fd + (e - 2359296);
    float4 v = *(const float4*)src;
    union { ushort_t us[4]; uint2 u; } t;
    t.us[0] = f2b(v.x); t.us[1] = f2b(v.y); t.us[2] = f2b(v.z); t.us[3] = f2b(v.w);
    *(uint2*)&out[e] = t.u;
}

// ---------------- bf16 MFMA GEMM: C[M,N] = A[M,K] @ B[K,N] (+bias)(+=C) ------
__global__ void __launch_bounds__(256)
gemm_bf(const ushort_t* __restrict__ A, const ushort_t* __restrict__ Bw,
        const float* __restrict__ bias, float* __restrict__ C,
        int M, int K, int N, int accum) {
    __shared__ __align__(16) ushort_t As[64][40];
    __shared__ __align__(16) ushort_t Bs[128][40];
    int tid = threadIdx.x;
    int wave = tid >> 6, lane = tid & 63;
    int wm = wave >> 1, wn = wave & 1;
    int quad = lane >> 4, l16 = lane & 15;
    int m0 = blockIdx.y * 64, n0 = blockIdx.x * 128;
    floatx4 zero = {0.f, 0.f, 0.f, 0.f};
    floatx4 acc[2][4];
    #pragma unroll
    for (int i = 0; i < 2; i++)
        #pragma unroll
        for (int j = 0; j < 4; j++) acc[i][j] = zero;
    int ar = tid >> 2, ac = (tid & 3) * 8;
    int bn = tid & 127, bkg = (tid >> 7) * 16;
    for (int k0 = 0; k0 < K; k0 += 32) {
        *(uint4*)&As[ar][ac] = *(const uint4*)(A + (size_t)(m0 + ar) * K + k0 + ac);
        {
            const ushort_t* bp = Bw + (size_t)(k0 + bkg) * N + n0 + bn;
            union { ushort_t us[16]; uint4 v[2]; } t;
            #pragma unroll
            for (int i = 0; i < 16; i++) t.us[i] = bp[(size_t)i * N];
            *(uint4*)&Bs[bn][bkg] = t.v[0];
            *(uint4*)&Bs[bn][bkg + 8] = t.v[1];
        }
        __syncthreads();
        short8 af[2], bf[4];
        #pragma unroll
        for (int i = 0; i < 2; i++) af[i] = *(const short8*)&As[wm * 32 + i * 16 + l16][quad * 8];
        #pragma unroll
        for (int j = 0; j < 4; j++) bf[j] = *(const short8*)&Bs[wn * 64 + j * 16 + l16][quad * 8];
        #pragma unroll
        for (int i = 0; i < 2; i++)
            #pragma unroll
            for (int j = 0; j < 4; j++)
                acc[i][j] = __builtin_amdgcn_mfma_f32_16x16x32_bf16(af[i], bf[j], acc[i][j], 0, 0, 0);
        __syncthreads();
    }
    #pragma unroll
    for (int i = 0; i < 2; i++)
        #pragma unroll
        for (int j = 0; j < 4; j++)
            #pragma unroll
            for (int r = 0; r < 4; r++) {
                int row = m0 + wm * 32 + i * 16 + quad * 4 + r;
                int col = n0 + wn * 64 + j * 16 + l16;
                float o = acc[i][j][r];
                if (bias) o += bias[col];
                float* cp = &C[(size_t)row * N + col];
                if (accum) o += *cp;
                *cp = o;
            }
}

// ---------------- fp32-A MFMA GEMM (embed only) ------------------------------
__global__ void __launch_bounds__(256)
gemm_mfma(const float* __restrict__ A, const float* __restrict__ Bw,
          const float* __restrict__ bias, float* __restrict__ C,
          int M, int K, int N, int accum) {
    __shared__ __align__(16) ushort_t As[64][40];
    __shared__ __align__(16) ushort_t Bs[64][40];
    int tid = threadIdx.x;
    int wave = tid >> 6, lane = tid & 63;
    int wm = wave >> 1, wn = wave & 1;
    int quad = lane >> 4, l16 = lane & 15;
    int m0 = blockIdx.y * 64, n0 = blockIdx.x * 64;
    floatx4 zero = {0.f, 0.f, 0.f, 0.f};
    floatx4 acc[2][2];
    acc[0][0] = zero; acc[0][1] = zero; acc[1][0] = zero; acc[1][1] = zero;
    int ar = tid >> 2, ac = (tid & 3) * 8;
    int bn = tid & 63, bk = (tid >> 6) * 8;
    for (int k0 = 0; k0 < K; k0 += 32) {
        {
            const float* ap = A + (size_t)(m0 + ar) * K + k0 + ac;
            union { ushort_t us[8]; uint4 v; } t;
            #pragma unroll
            for (int i = 0; i < 8; i++) t.us[i] = f2b(ap[i]);
            *(uint4*)&As[ar][ac] = t.v;
        }
        {
            const float* bp = Bw + (size_t)(k0 + bk) * N + n0 + bn;
            union { ushort_t us[8]; uint4 v; } t;
            #pragma unroll
            for (int i = 0; i < 8; i++) t.us[i] = f2b(bp[(size_t)i * N]);
            *(uint4*)&Bs[bn][bk] = t.v;
        }
        __syncthreads();
        short8 af[2], bf[2];
        #pragma unroll
        for (int i = 0; i < 2; i++) af[i] = *(const short8*)&As[wm * 32 + i * 16 + l16][quad * 8];
        #pragma unroll
        for (int j = 0; j < 2; j++) bf[j] = *(const short8*)&Bs[wn * 32 + j * 16 + l16][quad * 8];
        #pragma unroll
        for (int i = 0; i < 2; i++)
            #pragma unroll
            for (int j = 0; j < 2; j++)
                acc[i][j] = __builtin_amdgcn_mfma_f32_16x16x32_bf16(af[i], bf[j], acc[i][j], 0, 0, 0);
        __syncthreads();
    }
    #pragma unroll
    for (int i = 0; i < 2; i++)
        #pragma unroll
        for (int j = 0; j < 2; j++)
            #pragma unroll
            for (int r = 0; r < 4; r++) {
                int row = m0 + wm * 32 + i * 16 + quad * 4 + r;
                int col = n0 + wn * 32 + j * 16 + l16;
                float o = acc[i][j][r];
                if (bias) o += bias[col];
                float* cp = &C[(size_t)row * N + col];
                if (accum) o += *cp;
                *cp = o;
            }
}

// ---------------- sLSTM Wx as block-diagonal MFMA GEMM (bf16 A) --------------
__global__ void __launch_bounds__(256)
slstm_wx_mfma(const ushort_t* __restrict__ xc, const ushort_t* __restrict__ xln,
              const float* __restrict__ gw, float* __restrict__ Wx) {
    __shared__ __align__(16) ushort_t As[64][40];
    __shared__ __align__(16) ushort_t Bs[64][40];
    int gh = blockIdx.y; int g = gh >> 2, hh = gh & 3;
    const ushort_t* src = (g < 2) ? xc : xln;
    const float* w = gw + (size_t)gh * 4096;
    int tid = threadIdx.x;
    int wave = tid >> 6, lane = tid & 63;
    int wm = wave >> 1, wn = wave & 1;
    int quad = lane >> 4, l16 = lane & 15;
    int m0 = blockIdx.x * 64;
    floatx4 zero = {0.f, 0.f, 0.f, 0.f};
    floatx4 acc[2][2];
    acc[0][0] = zero; acc[0][1] = zero; acc[1][0] = zero; acc[1][1] = zero;
    int ar = tid >> 2, ac = (tid & 3) * 8;
    int bn = tid & 63, bk = (tid >> 6) * 8;
    #pragma unroll
    for (int kt = 0; kt < 2; kt++) {
        int k0 = kt * 32;
        *(uint4*)&As[ar][ac] = *(const uint4*)(src + (size_t)(m0 + ar) * 256 + hh * 64 + k0 + ac);
        {
            const float* bp = w + (size_t)bn * 64 + k0 + bk;
            union { ushort_t us[8]; uint4 v; } t;
            #pragma unroll
            for (int i = 0; i < 8; i++) t.us[i] = f2b(bp[i]);
            *(uint4*)&Bs[bn][bk] = t.v;
        }
        __syncthreads();
        short8 af[2], bf[2];
        #pragma unroll
        for (int i = 0; i < 2; i++) af[i] = *(const short8*)&As[wm * 32 + i * 16 + l16][quad * 8];
        #pragma unroll
        for (int j = 0; j < 2; j++) bf[j] = *(const short8*)&Bs[wn * 32 + j * 16 + l16][quad * 8];
        #pragma unroll
        for (int i = 0; i < 2; i++)
            #pragma unroll
            for (int j = 0; j < 2; j++)
                acc[i][j] = __builtin_amdgcn_mfma_f32_16x16x32_bf16(af[i], bf[j], acc[i][j], 0, 0, 0);
        __syncthreads();
    }
    #pragma unroll
    for (int i = 0; i < 2; i++)
        #pragma unroll
        for (int j = 0; j < 2; j++)
            #pragma unroll
            for (int r = 0; r < 4; r++) {
                int row = m0 + wm * 32 + i * 16 + quad * 4 + r;
                int col = wn * 32 + j * 16 + l16;
                Wx[(size_t)row * 1024 + g * 256 + hh * 64 + col] = acc[i][j][r];
            }
}

// ---------------- layernorm over 256, bf16 output ----------------------------
__global__ void __launch_bounds__(256)
layernorm256(const float* __restrict__ x, const float* __restrict__ w, ushort_t* __restrict__ y) {
    int n = blockIdx.x, t = threadIdx.x;
    float v = x[(size_t)n * 256 + t];
    float s = v, s2 = v * v;
    #pragma unroll
    for (int off = 32; off; off >>= 1) { s += __shfl_xor(s, off); s2 += __shfl_xor(s2, off); }
    __shared__ float ps[4], ps2[4];
    if ((t & 63) == 0) { ps[t >> 6] = s; ps2[t >> 6] = s2; }
    __syncthreads();
    float S = ps[0] + ps[1] + ps[2] + ps[3];
    float S2 = ps2[0] + ps2[1] + ps2[2] + ps2[3];
    float mu = S / 256.f, var = S2 / 256.f - mu * mu;
    y[(size_t)n * 256 + t] = f2b((v - mu) * rsqrtf(var + 1e-5f) * w[t]);
}

// ---------------- post-LN + selu (fp32 out) ---------------------------------
__global__ void __launch_bounds__(256)
postln_selu(const float* __restrict__ x, const float* __restrict__ w, float* __restrict__ y) {
    int n = blockIdx.x, t = threadIdx.x;
    float v = x[(size_t)n * 256 + t];
    float s = v, s2 = v * v;
    #pragma unroll
    for (int off = 32; off; off >>= 1) { s += __shfl_xor(s, off); s2 += __shfl_xor(s2, off); }
    __shared__ float ps[4], ps2[4];
    if ((t & 63) == 0) { ps[t >> 6] = s; ps2[t >> 6] = s2; }
    __syncthreads();
    float S = ps[0] + ps[1] + ps[2] + ps[3];
    float S2 = ps2[0] + ps2[1] + ps2[2] + ps2[3];
    float mu = S / 256.f, var = S2 / 256.f - mu * mu;
    float yn = (v - mu) * rsqrtf(var + 1e-5f) * w[t];
    y[(size_t)n * 256 + t] = 1.0507009873554805f * (yn > 0.f ? yn : 1.6732632423543772f * (expf(yn) - 1.f));
}

// ---------------- mLSTM: fused conv+silu+qkv+gates (bf16 q/k/v out) ----------
__global__ void __launch_bounds__(256)
fused_qkv(const float* __restrict__ xi, const float* __restrict__ cw,
          const float* __restrict__ cb,
          const float* __restrict__ qw, const float* __restrict__ kw,
          const float* __restrict__ vw,
          const float* __restrict__ igw, const float* __restrict__ igbias,
          const float* __restrict__ fgw, const float* __restrict__ fgbias,
          float* __restrict__ xca,
          ushort_t* __restrict__ q16, ushort_t* __restrict__ k16, ushort_t* __restrict__ v16,
          float* __restrict__ igo, float* __restrict__ fgo) {
    __shared__ float gpart[4][8];
    int tid = threadIdx.x;
    int idx = blockIdx.x * 256 + tid;
    int n = idx >> 7, hh = idx & 127;
    int b = n / S_, s = n - b * S_;
    int c0 = hh * 4;
    float4 hist[4];
    #pragma unroll
    for (int i = 0; i < 4; i++) {
        int sp = s - 3 + i;
        if (sp >= 0) hist[i] = *(const float4*)(xi + (size_t)(b * S_ + sp) * 1024 + c0);
        else hist[i] = (float4){0.f, 0.f, 0.f, 0.f};
    }
    float xm[4] = {hist[3].x, hist[3].y, hist[3].z, hist[3].w};
    float xc4[4];
    #pragma unroll
    for (int d = 0; d < 4; d++) {
        float y = cb[c0 + d];
        const float* cwp = cw + (c0 + d) * 4;
        float hv[4] = { d==0?hist[0].x:(d==1?hist[0].y:(d==2?hist[0].z:hist[0].w)),
                        d==0?hist[1].x:(d==1?hist[1].y:(d==2?hist[1].z:hist[1].w)),
                        d==0?hist[2].x:(d==1?hist[2].y:(d==2?hist[2].z:hist[2].w)),
                        xm[d] };
        #pragma unroll
        for (int i = 0; i < 4; i++) y += hv[i] * cwp[i];
        xc4[d] = siluf_(y);
    }
    *(float4*)(xca + (size_t)n * 512 + c0) = (float4){xc4[0], xc4[1], xc4[2], xc4[3]};
    float aq[4], ak[4], av[4];
    union { ushort_t us[4]; uint2 u; } qo, ko, vo;
    #pragma unroll
    for (int o = 0; o < 4; o++) {
        const float* qp = qw + (c0 + o) * 4;
        const float* kp = kw + (c0 + o) * 4;
        const float* vp = vw + (c0 + o) * 4;
        float q = 0.f, k = 0.f, v = 0.f;
        #pragma unroll
        for (int d = 0; d < 4; d++) {
            q += xc4[d] * qp[d];
            k += xc4[d] * kp[d];
            v += xm[d] * vp[d];
        }
        aq[o] = q; ak[o] = k; av[o] = v;
        qo.us[o] = f2b(q); ko.us[o] = f2b(k); vo.us[o] = f2b(v);
    }
    *(uint2*)(q16 + (size_t)n * 512 + c0) = qo.u;
    *(uint2*)(k16 + (size_t)n * 512 + c0) = ko.u;
    *(uint2*)(v16 + (size_t)n * 512 + c0) = vo.u;
    float gacc[8];
    #pragma unroll
    for (int hd = 0; hd < 4; hd++)
        #pragma unroll
        for (int wh = 0; wh < 2; wh++) {
            const float* w = (wh ? fgw : igw) + hd * 1536 + c0;
            float4 wq = *(const float4*)w;
            float4 wk = *(const float4*)(w + 512);
            float4 wv = *(const float4*)(w + 1024);
            float a = aq[0]*wq.x + aq[1]*wq.y + aq[2]*wq.z + aq[3]*wq.w
                    + ak[0]*wk.x + ak[1]*wk.y + ak[2]*wk.z + ak[3]*wk.w
                    + av[0]*wv.x + av[1]*wv.y + av[2]*wv.z + av[3]*wv.w;
            gacc[hd * 2 + wh] = a;
        }
    int lane = tid & 63, wave = tid >> 6;
    #pragma unroll
    for (int j = 0; j < 8; j++) {
        float a = gacc[j];
        #pragma unroll
        for (int off = 32; off; off >>= 1) a += __shfl_xor(a, off);
        if (lane == 0) gpart[wave][j] = a;
    }
    __syncthreads();
    if (tid < 16) {
        int token = tid >> 3, j = tid & 7;
        int hd = j >> 1, wh = j & 1;
        float val = gpart[token * 2][j] + gpart[token * 2 + 1][j]
                  + (wh ? fgbias : igbias)[hd];
        int nn = blockIdx.x * 2 + token;
        (wh ? fgo : igo)[(size_t)nn * 4 + hd] = val;
    }
}

// ---------------- mLSTM attention: MFMA flash + in-block cumsum scan ---------
__global__ void __launch_bounds__(256, 1)
mlstm_attn_mfma(const ushort_t* __restrict__ qb, const ushort_t* __restrict__ kb, const ushort_t* __restrict__ vb,
                const float* __restrict__ igo, const float* __restrict__ fgo,
                float* __restrict__ outb) {
    __shared__ __align__(16) ushort_t Kb[64 * 136];
    __shared__ __align__(16) ushort_t Vt[128 * 72];
    __shared__ __align__(16) ushort_t Pw[4][16 * 72];
    __shared__ float gv[208], lfv[208], mxv[208];
    int bh = blockIdx.x; int b = bh >> 2, h = bh & 3;
    int tid = threadIdx.x, wave = tid >> 6, lane = tid & 63;
    int quad = lane >> 4, l16 = lane & 15;
    if (tid < 64) {
        float vloc[4], ggl[4], gml[4], lf1[4];
        float lsum = 0.f;
        #pragma unroll
        for (int i = 0; i < 4; i++) {
            int s = tid * 4 + i;
            float f = (s < S_) ? fgo[(size_t)(b * S_ + s) * 4 + h] : 0.f;
            lsum += logsigf_(f);
            vloc[i] = lsum;
        }
        float x = lsum;
        #pragma unroll
        for (int off = 1; off < 64; off <<= 1) {
            float y = __shfl_up(x, off);
            if (tid >= off) x += y;
        }
        float excl = x - lsum;
        #pragma unroll
        for (int i = 0; i < 4; i++) lf1[i] = excl + vloc[i];
        float lmax = -1e30f;
        #pragma unroll
        for (int i = 0; i < 4; i++) {
            int s = tid * 4 + i;
            float ig_ = (s < S_) ? igo[(size_t)(b * S_ + s) * 4 + h] : -1e30f;
            ggl[i] = ig_ - lf1[i];
            lmax = fmaxf(lmax, ggl[i]);
            gml[i] = lmax;
        }
        float xm = lmax;
        #pragma unroll
        for (int off = 1; off < 64; off <<= 1) {
            float y = __shfl_up(xm, off);
            if (tid >= off) xm = fmaxf(xm, y);
        }
        float exclm = __shfl_up(xm, 1);
        if (tid == 0) exclm = -1e30f;
        #pragma unroll
        for (int i = 0; i < 4; i++) {
            int s = tid * 4 + i;
            if (s < 208) {
                if (s < S_) {
                    lfv[s] = lf1[i];
                    gv[s] = ggl[i];
                    mxv[s] = fmaxf(exclm, gml[i]);
                } else { lfv[s] = 0.f; gv[s] = 0.f; mxv[s] = 0.f; }
            }
        }
    }
    floatx4 zero = {0.f, 0.f, 0.f, 0.f};
    float rs[4][4];
    floatx4 accv[4][8];
    #pragma unroll
    for (int qi = 0; qi < 4; qi++) {
        #pragma unroll
        for (int r = 0; r < 4; r++) rs[qi][r] = 0.f;
        #pragma unroll
        for (int dt = 0; dt < 8; dt++) accv[qi][dt] = zero;
    }
    const float scale = 0.08838834764831845f;
    int trow = tid >> 4, d0 = (tid & 15) * 8;
    for (int c = 0; c < 4; c++) {
        __syncthreads();
        #pragma unroll
        for (int i = 0; i < 4; i++) {
            int tl = trow + 16 * i;
            int t = c * 64 + tl;
            union { ushort_t us[8]; uint4 v; } kk, vv;
            if (t < S_) {
                kk.v = *(const uint4*)(kb + (size_t)(b * S_ + t) * 512 + h * 128 + d0);
                vv.v = *(const uint4*)(vb + (size_t)(b * S_ + t) * 512 + h * 128 + d0);
            } else {
                kk.v = (uint4){0, 0, 0, 0};
                vv.v = (uint4){0, 0, 0, 0};
            }
            *(uint4*)&Kb[tl * 136 + d0] = kk.v;
            #pragma unroll
            for (int ii = 0; ii < 8; ii++) Vt[(d0 + ii) * 72 + tl] = vv.us[ii];
        }
        __syncthreads();
        for (int qi = 0; qi < 4; qi++) {
            int qt = wave + 4 * qi;
            if (qt >= NQT || qt < 4 * c) continue;
            uint4 z4 = {0, 0, 0, 0};
            for (int z = lane; z < 144; z += 64) ((uint4*)Pw[wave])[z] = z4;
            int srow = qt * 16 + l16;
            const ushort_t* qp = qb + (size_t)(b * S_ + min(srow, S_ - 1)) * 512 + h * 128 + quad * 8;
            short8 af[4];
            #pragma unroll
            for (int ks = 0; ks < 4; ks++) af[ks] = *(const short8*)(qp + 32 * ks);
            int ktmax_l = min(qt, 4 * c + 3) - 4 * c;
            for (int ktl = 0; ktl <= ktmax_l; ktl++) {
                floatx4 acc = zero;
                #pragma unroll
                for (int ks = 0; ks < 4; ks++) {
                    short8 bf = *(const short8*)&Kb[(ktl * 16 + l16) * 136 + quad * 8 + 32 * ks];
                    acc = __builtin_amdgcn_mfma_f32_16x16x32_bf16(af[ks], bf, acc, 0, 0, 0);
                }
                int tcol = c * 64 + ktl * 16 + l16;
                float gt = gv[tcol];
                #pragma unroll
                for (int r = 0; r < 4; r++) {
                    int s = qt * 16 + quad * 4 + r;
                    bool valid = (tcol <= s) && (tcol < S_);
                    float w = valid ? expf(gt - mxv[s]) : 0.f;
                    float p = acc[r] * scale * w;
                    rs[qi][r] += p;
                    Pw[wave][(quad * 4 + r) * 72 + ktl * 16 + l16] = f2b(p);
                }
            }
            #pragma unroll
            for (int dt = 0; dt < 8; dt++) {
                floatx4 a = accv[qi][dt];
                #pragma unroll
                for (int ks = 0; ks < 2; ks++) {
                    short8 ap = *(const short8*)&Pw[wave][l16 * 72 + quad * 8 + 32 * ks];
                    short8 bp = *(const short8*)&Vt[(dt * 16 + l16) * 72 + quad * 8 + 32 * ks];
                    a = __builtin_amdgcn_mfma_f32_16x16x32_bf16(ap, bp, a, 0, 0, 0);
                }
                accv[qi][dt] = a;
            }
        }
    }
    for (int qi = 0; qi < 4; qi++) {
        int qt = wave + 4 * qi;
        if (qt >= NQT) continue;
        float nrm[4];
        #pragma unroll
        for (int r = 0; r < 4; r++) {
            float v = rs[qi][r];
            v += __shfl_xor(v, 1); v += __shfl_xor(v, 2);
            v += __shfl_xor(v, 4); v += __shfl_xor(v, 8);
            int s = qt * 16 + quad * 4 + r;
            nrm[r] = fmaxf(fabsf(v), expf(-(lfv[s] + mxv[s]))) + 1e-6f;
        }
        #pragma unroll
        for (int dt = 0; dt < 8; dt++)
            #pragma unroll
            for (int r = 0; r < 4; r++) {
                int s = qt * 16 + quad * 4 + r;
                if (s < S_)
                    outb[(size_t)(b * S_ + s) * 512 + h * 128 + dt * 16 + l16] = accv[qi][dt][r] / nrm[r];
            }
    }
}

// ---------------- mLSTM: fused per-head LN + h_state -> bf16 -----------------
__global__ void __launch_bounds__(512)
mhln_hstate(const float* __restrict__ hatt, const float* __restrict__ w,
            const float* __restrict__ xca, const float* __restrict__ xi,
            const float* __restrict__ skip, ushort_t* __restrict__ out16) {
    int n = blockIdx.x, t = threadIdx.x;
    float v = hatt[(size_t)n * 512 + t];
    float s = v, s2 = v * v;
    #pragma unroll
    for (int off = 32; off; off >>= 1) { s += __shfl_xor(s, off); s2 += __shfl_xor(s2, off); }
    __shared__ float ps[8], ps2[8];
    if ((t & 63) == 0) { ps[t >> 6] = s; ps2[t >> 6] = s2; }
    __syncthreads();
    int hd = t >> 7;
    float S = ps[hd * 2] + ps[hd * 2 + 1], S2 = ps2[hd * 2] + ps2[hd * 2 + 1];
    float mu = S / 128.f, var = S2 / 128.f - mu * mu;
    float hn = (v - mu) * rsqrtf(var + 1e-5f) * w[t];
    float z = xi[(size_t)n * 1024 + 512 + t];
    out16[(size_t)n * 512 + t] = f2b((hn + skip[t] * xca[(size_t)n * 512 + t]) * siluf_(z));
}

// ---------------- sLSTM: causal conv (256 ch) + silu, bf16 in/out ------------
__global__ void conv_silu_s(const ushort_t* __restrict__ xln, const float* __restrict__ cw,
                            const float* __restrict__ cb, ushort_t* __restrict__ xc) {
    int idx = blockIdx.x * blockDim.x + threadIdx.x;
    if (idx >= NTOK * 256) return;
    int n = idx >> 8, c = idx & 255;
    int b = n / S_, s = n - b * S_;
    float y = cb[c];
    #pragma unroll
    for (int i = 0; i < 4; i++) {
        int sp = s - 3 + i;
        if (sp >= 0) y += bf2f(xln[(size_t)(b * S_ + sp) * 256 + c]) * cw[c * 4 + i];
    }
    xc[idx] = f2b(siluf_(y));
}

// ---------------- sLSTM: recurrence v5 — 4 waves, LDS weights ----------------
// 256 thr: thread = (g = tid>>6, o = tid&63). Weights LDS [256][68] fp32
// (lane bank-stride 4 -> conflict-free b128). hs reads are broadcasts.
// Theory: previous 8-wave variants were barrier/latency-bound (~2500cyc/step
// regardless of weight residency); 4 waves + no shfl halves that overhead.
__global__ void __launch_bounds__(256)
slstm_rec(const float* __restrict__ Wx, const float* __restrict__ rw,
          const float* __restrict__ bias, float* __restrict__ ys) {
    __shared__ __align__(16) float wl[256][68];
    __shared__ __align__(16) float hs[64];
    __shared__ float raws[4][64];
    int b = blockIdx.x >> 2, h = blockIdx.x & 3;
    int tid = threadIdx.x;
    int g = tid >> 6, o = tid & 63;
    const float* wp = rw + (size_t)(((g * 4 + h) * 64 + o)) * 64;
    #pragma unroll
    for (int i = 0; i < 16; i++) *(float4*)&wl[tid][i * 4] = *(const float4*)&wp[i * 4];
    float bi = bias[(g * 4 + h) * 64 + o];
    if (tid < 64) hs[tid] = 0.f;
    float c_ = 0.f, n_ = 0.f, m_ = 0.f;
    size_t wxbase = (size_t)(b * S_) * 1024 + g * 256 + h * 64 + o;
    float wx_cur = Wx[wxbase];
    __syncthreads();
    for (int s = 0; s < S_; s++) {
        float wx_next = (s + 1 < S_) ? Wx[wxbase + (size_t)(s + 1) * 1024] : 0.f;
        float a0 = 0.f, a1 = 0.f, a2 = 0.f, a3 = 0.f;
        #pragma unroll
        for (int d4 = 0; d4 < 16; d4++) {
            float4 wv = *(const float4*)&wl[tid][d4 * 4];
            float4 hv = *(const float4*)&hs[d4 * 4];
            a0 += hv.x * wv.x;
            a1 += hv.y * wv.y;
            a2 += hv.z * wv.z;
            a3 += hv.w * wv.w;
        }
        raws[g][o] = (a0 + a1) + (a2 + a3) + wx_cur + bi;
        __syncthreads();
        float ir = raws[0][o], fr = raws[1][o], zr = raws[2][o], orr = raws[3][o];
        float lfpm = m_ + logsigf_(fr);
        float mn = fmaxf(ir, lfpm);
        float ig = expf(ir - mn), fg = expf(lfpm - mn);
        c_ = fg * c_ + ig * tanhf(zr);
        n_ = fg * n_ + ig;
        m_ = mn;
        float hn = sigmoidf_(orr) * (c_ / n_);
        if (g == 0) {
            hs[o] = hn;
            ys[(size_t)(b * S_ + s) * 256 + h * 64 + o] = hn;
        }
        __syncthreads();
        wx_cur = wx_next;
    }
}

// ---------------- sLSTM: fused groupnorm+residual + LN2 -> bf16 --------------
__global__ void __launch_bounds__(256)
slstm_post(const float* __restrict__ ys, const float* __restrict__ gn_w,
           float* __restrict__ h, const float* __restrict__ ln2_w,
           ushort_t* __restrict__ ln16) {
    int n = blockIdx.x, t = threadIdx.x;
    float v = ys[(size_t)n * 256 + t];
    float s = v, s2 = v * v;
    #pragma unroll
    for (int off = 32; off; off >>= 1) { s += __shfl_xor(s, off); s2 += __shfl_xor(s2, off); }
    float mu = s / 64.f, var = s2 / 64.f - mu * mu;
    float hv = h[(size_t)n * 256 + t] + (v - mu) * rsqrtf(var + 1e-5f) * gn_w[t];
    h[(size_t)n * 256 + t] = hv;
    float S = hv, S2 = hv * hv;
    #pragma unroll
    for (int off = 32; off; off >>= 1) { S += __shfl_xor(S, off); S2 += __shfl_xor(S2, off); }
    __shared__ float ps[4], ps2[4];
    if ((t & 63) == 0) { ps[t >> 6] = S; ps2[t >> 6] = S2; }
    __syncthreads();
    float St = ps[0] + ps[1] + ps[2] + ps[3];
    float S2t = ps2[0] + ps2[1] + ps2[2] + ps2[3];
    float mu2 = St / 256.f, var2 = S2t / 256.f - mu2 * mu2;
    ln16[(size_t)n * 256 + t] = f2b((hv - mu2) * rsqrtf(var2 + 1e-5f) * ln2_w[t]);
}

// ---------------- FFN: gelu(gate)*up -> bf16 ---------------------------------
__global__ void ffn_act(const float* __restrict__ up, ushort_t* __restrict__ act) {
    int idx = blockIdx.x * blockDim.x + threadIdx.x;
    if (idx >= NTOK * 384) return;
    int n = idx / 384, j = idx - n * 384;
    float g = up[(size_t)n * 768 + j], u = up[(size_t)n * 768 + 384 + j];
    float t = tanhf(0.7978845608028654f * (g + 0.044715f * g * g * g));
    act[idx] = f2b(0.5f * g * (1.f + t) * u);
}

// ---------------- pooling + heads --------------------------------------------
__global__ void pool_k(const float* __restrict__ a, float* __restrict__ pooled) {
    int b = blockIdx.x, e = threadIdx.x;
    float s = 0.f;
    for (int t = 0; t < S_; t++) s += a[(size_t)(b * S_ + t) * 256 + e];
    pooled[b * 256 + e] = s / (float)S_;
}

__global__ void heads_k(const float* __restrict__ pooled,
                        const float* __restrict__ we, const float* __restrict__ be,
                        const float* __restrict__ ws, const float* __restrict__ bs,
                        float* __restrict__ out) {
    int i = blockIdx.x * blockDim.x + threadIdx.x;
    if (i < B_ * 7) {
        int b = i / 7, o = i - b * 7;
        float a = be[o];
        for (int e = 0; e < 256; e++) a += pooled[b * 256 + e] * we[e * 7 + o];
        out[b * 7 + o] = a;
    } else if (i < B_ * 7 + B_ * 3) {
        int j = i - B_ * 7;
        int b = j / 3, o = j - b * 3;
        float a = bs[o];
        for (int e = 0; e < 256; e++) a += pooled[b * 256 + e] * ws[e * 3 + o];
        out[B_ * 7 + b * 3 + o] = a;
    }
}

// =============================================================================
extern "C" void kernel_launch(void* const* d_in, const int* in_sizes, int n_in,
                              void* d_out, int out_size, void* d_ws, size_t ws_size,
                              hipStream_t stream) {
    (void)in_sizes; (void)n_in; (void)out_size; (void)ws_size;
    const float* x          = (const float*)d_in[0];
    const float* w_down     = (const float*)d_in[1];
    const float* b_down     = (const float*)d_in[2];
    const float* m_ln_w     = (const float*)d_in[3];
    const float* m_proj_up  = (const float*)d_in[4];
    const float* m_conv_w   = (const float*)d_in[5];
    const float* m_conv_b   = (const float*)d_in[6];
    const float* m_q_w      = (const float*)d_in[7];
    const float* m_k_w      = (const float*)d_in[8];
    const float* m_v_w      = (const float*)d_in[9];
    const float* m_ig_w     = (const float*)d_in[10];
    const float* m_ig_b     = (const float*)d_in[11];
    const float* m_fg_w     = (const float*)d_in[12];
    const float* m_fg_b     = (const float*)d_in[13];
    const float* m_skip     = (const float*)d_in[14];
    const float* m_outnorm  = (const float*)d_in[15];
    const float* m_proj_dn  = (const float*)d_in[16];
    const float* s_ln_w     = (const float*)d_in[17];
    const float* s_conv_w   = (const float*)d_in[18];
    const float* s_conv_b   = (const float*)d_in[19];
    const float* s_gate_w   = (const float*)d_in[20];
    const float* s_rec_w    = (const float*)d_in[21];
    const float* s_bias     = (const float*)d_in[22];
    const float* s_gn_w     = (const float*)d_in[23];
    const float* s_ln2_w    = (const float*)d_in[24];
    const float* s_ffn_up   = (const float*)d_in[25];
    const float* s_ffn_dn   = (const float*)d_in[26];
    const float* post_ln_w  = (const float*)d_in[27];
    const float* w_emo      = (const float*)d_in[28];
    const float* b_emo      = (const float*)d_in[29];
    const float* w_sen      = (const float*)d_in[30];
    const float* b_sen      = (const float*)d_in[31];

    float* W    = (float*)d_ws;
    float* h    = W;
    float* lnb  = h    + (size_t)NTOK * 256;
    float* big0 = lnb  + (size_t)NTOK * 256;
    float* xca  = big0 + (size_t)NTOK * 1024;
    float* qb   = xca  + (size_t)NTOK * 512;
    float* kb   = qb   + (size_t)NTOK * 512;
    float* vb   = kb   + (size_t)NTOK * 512;
    float* hatt = vb   + (size_t)NTOK * 512;
    float* igo  = hatt + (size_t)NTOK * 512;
    float* fgo  = igo  + (size_t)NTOK * 4;
    float* lfcb = fgo  + (size_t)NTOK * 4;
    float* Mxb  = lfcb + (size_t)256 * (S_ + 1);
    float* pooled = Mxb + (size_t)256 * S_;
    // bf16 overlays
    ushort_t* lnb16 = (ushort_t*)lnb;
    ushort_t* qb16  = (ushort_t*)qb;
    ushort_t* kb16  = (ushort_t*)kb;
    ushort_t* vb16  = (ushort_t*)vb;
    ushort_t* hat16 = qb16 + (size_t)NTOK * 512;
    ushort_t* xc16  = (ushort_t*)(vb16 + (size_t)NTOK * 512);
    ushort_t* wpk   = (ushort_t*)(pooled + 64 * 256);
    ushort_t* wp_pu = wpk;                             // 5*256*1024
    ushort_t* wp_pd = wp_pu + 5 * 262144;              // 5*512*256
    ushort_t* wp_fu = wp_pd + 5 * 131072;              // 2*256*768
    ushort_t* wp_fd = wp_fu + 2 * 196608;              // 2*384*256

    cvt_all<<<(638976 + 255) / 256, 256, 0, stream>>>(m_proj_up, m_proj_dn, s_ffn_up, s_ffn_dn, wpk, 638976);

    gemm_mfma<<<dim3(256 / 64, NTOK / 64), 256, 0, stream>>>(x, w_down, b_down, h, NTOK, 1024, 256, 0);

    int mi = 0, si = 0;
    for (int blk = 0; blk < 7; blk++) {
        if (blk == 1 || blk == 4) {
            layernorm256<<<NTOK, 256, 0, stream>>>(h, s_ln_w + si * 256, lnb16);
            conv_silu_s<<<(NTOK * 256 + 255) / 256, 256, 0, stream>>>(lnb16, s_conv_w + si * 1024, s_conv_b + si * 256, xc16);
            slstm_wx_mfma<<<dim3(NTOK / 64, 16), 256, 0, stream>>>(xc16, lnb16, s_gate_w + (size_t)si * 65536, big0);
            slstm_rec<<<256, 256, 0, stream>>>(big0, s_rec_w + (size_t)si * 65536, s_bias + si * 1024, hatt);
            slstm_post<<<NTOK, 256, 0, stream>>>(hatt, s_gn_w + si * 256, h, s_ln2_w + si * 256, lnb16);
            gemm_bf<<<dim3(768 / 128, NTOK / 64), 256, 0, stream>>>(lnb16, wp_fu + (size_t)si * 196608, nullptr, big0, NTOK, 256, 768, 0);
            ffn_act<<<(NTOK * 384 + 255) / 256, 256, 0, stream>>>(big0, hat16);
            gemm_bf<<<dim3(256 / 128, NTOK / 64), 256, 0, stream>>>(hat16, wp_fd + (size_t)si * 98304, nullptr, h, NTOK, 384, 256, 1);
            si++;
        } else {
            layernorm256<<<NTOK, 256, 0, stream>>>(h, m_ln_w + mi * 256, lnb16);
            gemm_bf<<<dim3(1024 / 128, NTOK / 64), 256, 0, stream>>>(lnb16, wp_pu + (size_t)mi * 262144, nullptr, big0, NTOK, 256, 1024, 0);
            fused_qkv<<<NTOK / 2, 256, 0, stream>>>(big0, m_conv_w + mi * 2048, m_conv_b + mi * 512,
                                                    m_q_w + mi * 2048, m_k_w + mi * 2048, m_v_w + mi * 2048,
                                                    m_ig_w + mi * 6144, m_ig_b + mi * 4,
                                                    m_fg_w + mi * 6144, m_fg_b + mi * 4,
                                                    xca, qb16, kb16, vb16, igo, fgo);
            mlstm_attn_mfma<<<256, 256, 0, stream>>>(qb16, kb16, vb16, igo, fgo, hatt);
            mhln_hstate<<<NTOK, 512, 0, stream>>>(hatt, m_outnorm + mi * 512, xca, big0, m_skip + mi * 512, hat16);
            gemm_bf<<<dim3(256 / 128, NTOK / 64), 256, 0, stream>>>(hat16, wp_pd + (size_t)mi * 131072, nullptr, h, NTOK, 512, 256, 1);
            mi++;
        }
    }

    postln_selu<<<NTOK, 256, 0, stream>>>(h, post_ln_w, xca);
    pool_k<<<B_, 256, 0, stream>>>(xca, pooled);
    heads_k<<<3, 256, 0, stream>>>(pooled, w_emo, b_emo, w_sen, b_sen, (float*)d_out);
}